// Round 12
// baseline (165.392 us; speedup 1.0000x reference)
//
#include <hip/hip_runtime.h>
#include <hip/hip_bf16.h>

#define LL 4096
#define DD 512
#define BB 8
#define KSEL 41

typedef __attribute__((ext_vector_type(4))) float f32x4;
typedef __attribute__((ext_vector_type(8))) short short8;

__device__ __forceinline__ ushort f2bf(float x) {
  __hip_bfloat16 h = __float2bfloat16(x);
  return *reinterpret_cast<ushort*>(&h);
}

__device__ __forceinline__ void g2lds16(const void* g, void* l) {
  __builtin_amdgcn_global_load_lds(
      (const __attribute__((address_space(1))) unsigned int*)g,
      (__attribute__((address_space(3))) unsigned int*)l, 16, 0, 0);
}

// ---- K1: column sums, wave-sequential streaming + nontemporal loads ----
__global__ __launch_bounds__(512) void k_colsum(const float* __restrict__ q,
                                                const float* __restrict__ kk,
                                                float* __restrict__ qpart,
                                                float* __restrict__ kpart) {
  int lc = blockIdx.x, b = blockIdx.y, which = blockIdx.z;
  const float* src = which ? kk : q;
  float* part = which ? kpart : qpart;
  int lane = threadIdx.x & 63, w = threadIdx.x >> 6;
  int c8 = lane * 8;
  const float* p = src + ((size_t)b * LL + (size_t)lc * 256 + w * 32) * DD + c8;
  float a0 = 0, a1 = 0, a2 = 0, a3 = 0, a4 = 0, a5 = 0, a6 = 0, a7 = 0;
#pragma unroll 8
  for (int l = 0; l < 32; ++l) {
    f32x4 x = __builtin_nontemporal_load((const f32x4*)(p + (size_t)l * DD));
    f32x4 y = __builtin_nontemporal_load((const f32x4*)(p + (size_t)l * DD + 4));
    a0 += x[0]; a1 += x[1]; a2 += x[2]; a3 += x[3];
    a4 += y[0]; a5 += y[1]; a6 += y[2]; a7 += y[3];
  }
  float* dst = &part[((size_t)b * 128 + lc * 8 + w) * DD + c8];
  f32x4 o0 = {a0, a1, a2, a3}, o1 = {a4, a5, a6, a7};
  *(f32x4*)dst = o0;
  *(f32x4*)(dst + 4) = o1;
}

// ---- K2: merged {proj partials + inline colsum reduce} + {WvoT} + {last-block stats} ----
// blocks 0..23: proj (jc = bid&7, which = bid>>3); blocks 24..151: wvot.
// The LAST proj block to finish (atomic counter) runs the stats reduction.
struct StatsSm {
  float Sq[BB][DD];
  float Sk[BB][DD];
  float mvs[BB][64];
  float mab[64];
  int idxs[64];
};
union ProjSm {
  float ss[BB][64];
  float wv[8][512];
  StatsSm st;
};

__global__ __launch_bounds__(256) void k_projw(
    const float* __restrict__ qpart, const float* __restrict__ kpart,
    const float* __restrict__ Wq, const float* __restrict__ Wk,
    const float* __restrict__ bv, const float* __restrict__ Wo,
    const float* __restrict__ Wv,
    const float* __restrict__ bq, const float* __restrict__ bk,
    const float* __restrict__ bo,
    float* __restrict__ partQ, float* __restrict__ partK,
    float* __restrict__ partO, ushort* __restrict__ WT,
    int* __restrict__ counter,
    int* __restrict__ idx_out, float* __restrict__ wts_out,
    float* __restrict__ bvo_out) {
  __shared__ ProjSm u;
  __shared__ int amLast;
  int bid = blockIdx.x;
  int tid = threadIdx.x;

  if (bid >= 24) {
    // ---- wvot path: WT[c][j0..j0+8) = bf16((Wv @ Wo)^T) ----
    int b2 = bid - 24;
    int cb = b2 & 1, jg = b2 >> 1;
    int c = cb * 256 + tid;
    int j0 = jg * 8;
    for (int t = tid; t < 8 * 512; t += 256)
      u.wv[t >> 9][t & 511] = Wv[(size_t)(j0 + (t >> 9)) * DD + (t & 511)];
    __syncthreads();
    float acc[8] = {0, 0, 0, 0, 0, 0, 0, 0};
    for (int m = 0; m < DD; ++m) {
      float wo = Wo[(size_t)m * DD + c];
#pragma unroll
      for (int j = 0; j < 8; ++j) acc[j] += u.wv[j][m] * wo;
    }
    ushort4 o0, o1;
    o0.x = f2bf(acc[0]); o0.y = f2bf(acc[1]); o0.z = f2bf(acc[2]); o0.w = f2bf(acc[3]);
    o1.x = f2bf(acc[4]); o1.y = f2bf(acc[5]); o1.z = f2bf(acc[6]); o1.w = f2bf(acc[7]);
    *(ushort4*)&WT[(size_t)c * DD + j0] = o0;
    *(ushort4*)&WT[(size_t)c * DD + j0 + 4] = o1;
    return;
  }

  // ---- proj path ----
  int jc = bid & 7, which = bid >> 3;
  int j0 = jc * 64;
  if (which == 2) {
    float a0 = 0.f, a1 = 0.f;
    for (int j = 0; j < 64; ++j) {
      float b = bv[j0 + j];
      a0 += b * Wo[(size_t)(j0 + j) * DD + tid];
      a1 += b * Wo[(size_t)(j0 + j) * DD + tid + 256];
    }
    partO[(size_t)jc * DD + tid] = a0;
    partO[(size_t)jc * DD + tid + 256] = a1;
  } else {
    const float* part_in = which ? kpart : qpart;
    const float* W = which ? Wk : Wq;
    for (int e = tid; e < BB * 64; e += 256) {
      int b = e >> 6, j = e & 63;
      float s = 0.f;
#pragma unroll 8
      for (int p = 0; p < 128; ++p)
        s += part_in[((size_t)b * 128 + p) * DD + j0 + j];
      u.ss[b][j] = s;
    }
    __syncthreads();
    float a[BB][2];
#pragma unroll
    for (int b = 0; b < BB; ++b) { a[b][0] = 0.f; a[b][1] = 0.f; }
    for (int j = 0; j < 64; ++j) {
      float w0 = W[(size_t)(j0 + j) * DD + tid];
      float w1 = W[(size_t)(j0 + j) * DD + tid + 256];
#pragma unroll
      for (int b = 0; b < BB; ++b) {
        float sv = u.ss[b][j];
        a[b][0] += sv * w0;
        a[b][1] += sv * w1;
      }
    }
    float* part = which ? partK : partQ;
#pragma unroll
    for (int b = 0; b < BB; ++b) {
      part[((size_t)jc * BB + b) * DD + tid] = a[b][0];
      part[((size_t)jc * BB + b) * DD + tid + 256] = a[b][1];
    }
    __syncthreads();
  }

  // ---- last-block stats (replaces k_stats2 launch) ----
  __threadfence();
  if (tid == 0) amLast = (atomicAdd(counter, 1) == 23);
  __syncthreads();
  if (!amLast) return;
  __threadfence();

  for (int c = tid; c < DD; c += 256) {
    float bqv = bq[c] * (float)LL, bkv = bk[c] * (float)LL;
#pragma unroll
    for (int b = 0; b < BB; ++b) {
      float aq = 0.f, ak = 0.f;
#pragma unroll
      for (int j = 0; j < 8; ++j) {
        aq += partQ[((size_t)j * BB + b) * DD + c];
        ak += partK[((size_t)j * BB + b) * DD + c];
      }
      u.st.Sq[b][c] = aq + bqv;
      u.st.Sk[b][c] = ak + bkv;
    }
    float ao = 0.f;
#pragma unroll
    for (int j = 0; j < 8; ++j) ao += partO[(size_t)j * DD + c];
    bvo_out[c] = ao + bo[c];
  }
  __syncthreads();
  for (int e = tid; e < BB * 64; e += 256) {
    int b = e >> 6, d = e & 63;
    float s = 0.f;
#pragma unroll
    for (int h = 0; h < 8; ++h) s += u.st.Sq[b][h * 64 + d] * u.st.Sk[b][h * 64 + d];
    u.st.mvs[b][d] = s * (1.0f / ((float)LL * 8.0f));
  }
  __syncthreads();
  if (tid < 64) {
    float s = 0.f;
#pragma unroll
    for (int b = 0; b < BB; ++b) s += u.st.mvs[b][tid];
    u.st.mab[tid] = s * 0.125f;
  }
  __syncthreads();
  if (tid < 64) {
    float x = u.st.mab[tid];
    int r = 0;
    for (int d = 0; d < 64; ++d) {
      float y = u.st.mab[d];
      r += (y > x || (y == x && d < tid)) ? 1 : 0;
    }
    if (r < KSEL) { u.st.idxs[r] = tid; idx_out[r] = tid; }
  }
  __syncthreads();
  if (tid < BB) {
    int b = tid;
    float mx = -3.4e38f;
    for (int i = 0; i < KSEL; ++i) mx = fmaxf(mx, u.st.mvs[b][u.st.idxs[i]]);
    float s = 0.f;
    for (int i = 0; i < KSEL; ++i) s += expf(u.st.mvs[b][u.st.idxs[i]] - mx);
    float inv = 1.f / s;
    for (int i = 0; i < KSEL; ++i)
      wts_out[b * 64 + i] = expf(u.st.mvs[b][u.st.idxs[i]] - mx) * inv;
  }
}

// -------- K3: vagg = conv(v) via MFMA --------
__global__ __launch_bounds__(256) void k_conv(const float* __restrict__ v,
                                              const int* __restrict__ idx,
                                              const float* __restrict__ wts,
                                              ushort* __restrict__ vagg) {
  __shared__ ushort vwinT[128 * 136];
  __shared__ ushort Mlds[64 * 136];
  __shared__ float coefw[256];
  int lt = blockIdx.x;
  int ch0 = blockIdx.y * 128;
  int b = blockIdx.z;
  int tid = threadIdx.x;
  int l0 = lt * 64;

  coefw[tid] = 0.f;
  __syncthreads();
  if (tid < KSEL) coefw[64 + idx[tid]] = wts[b * 64 + tid];
  __syncthreads();

  {
    int c = tid & 127;
    int jh = tid >> 7;
    const float* vb = v + (size_t)b * LL * DD + ch0 + c;
#pragma unroll
    for (int it = 0; it < 8; ++it) {
      int j0 = (it * 2 + jh) * 8;
      union { unsigned int u[4]; short8 s; } pk;
#pragma unroll
      for (int p = 0; p < 4; ++p) {
        int ja = (l0 + j0 + 2 * p) & (LL - 1);
        int jb = (l0 + j0 + 2 * p + 1) & (LL - 1);
        float lo = vb[(size_t)ja * DD];
        float hi = vb[(size_t)jb * DD];
        pk.u[p] = (unsigned)f2bf(lo) | ((unsigned)f2bf(hi) << 16);
      }
      *(short8*)&vwinT[c * 136 + j0] = pk.s;
    }
  }
#pragma unroll
  for (int it = 0; it < 8; ++it) {
    int e = (it * 256 + tid) * 4;
    int r = e >> 7, j0 = e & 127;
    ushort4 m4;
    m4.x = f2bf(coefw[64 + j0 + 0 - r]);
    m4.y = f2bf(coefw[64 + j0 + 1 - r]);
    m4.z = f2bf(coefw[64 + j0 + 2 - r]);
    m4.w = f2bf(coefw[64 + j0 + 3 - r]);
    *(ushort4*)&Mlds[r * 136 + j0] = m4;
  }
  __syncthreads();

  int lane = tid & 63, w = tid >> 6;
  int r15 = lane & 15, g = lane >> 4;
  f32x4 acc[4][2] = {};
#pragma unroll
  for (int ks = 0; ks < 4; ++ks) {
    int kc = ks * 4 + g;
    short8 av[4], bvv[2];
#pragma unroll
    for (int m = 0; m < 4; ++m)
      av[m] = *(const short8*)&Mlds[(m * 16 + r15) * 136 + kc * 8];
#pragma unroll
    for (int n = 0; n < 2; ++n)
      bvv[n] = *(const short8*)&vwinT[(w * 32 + n * 16 + r15) * 136 + kc * 8];
#pragma unroll
    for (int m = 0; m < 4; ++m)
#pragma unroll
      for (int n = 0; n < 2; ++n)
        acc[m][n] = __builtin_amdgcn_mfma_f32_16x16x32_bf16(av[m], bvv[n], acc[m][n], 0, 0, 0);
  }

  ushort* vout = vagg + ((size_t)b * LL + l0) * DD + ch0;
#pragma unroll
  for (int m = 0; m < 4; ++m)
#pragma unroll
    for (int n = 0; n < 2; ++n)
#pragma unroll
      for (int r = 0; r < 4; ++r) {
        int row = m * 16 + g * 4 + r;
        int col = w * 32 + n * 16 + r15;
        vout[(size_t)row * DD + col] = f2bf(acc[m][n][r]);
      }
}

// -------- K4: out = vagg(bf16) @ Wvo(bf16, stored transposed) + bvo  (f32) --------
__global__ __launch_bounds__(256) void k_gemm(const ushort* __restrict__ A,
                                              const ushort* __restrict__ BT,
                                              const float* __restrict__ bias,
                                              float* __restrict__ C) {
  __shared__ ushort lA[128 * 64];
  __shared__ ushort lB[128 * 64];
  int bcol = blockIdx.x * 128;
  int brow = blockIdx.y * 128;
  int tid = threadIdx.x;
  int lane = tid & 63, wid = tid >> 6;
  int wr = wid >> 1, wc = wid & 1;
  int r15 = lane & 15, g = lane >> 4;
  f32x4 acc[4][4] = {};
  for (int k0 = 0; k0 < DD; k0 += 64) {
#pragma unroll
    for (int it = 0; it < 4; ++it) {
      int ch = it * 256 + tid;
      int row = ch >> 3;
      int clg = (ch & 7) ^ (row & 7);
      g2lds16(A + (size_t)(brow + row) * DD + k0 + clg * 8, &lA[ch * 8]);
      g2lds16(BT + (size_t)(bcol + row) * DD + k0 + clg * 8, &lB[ch * 8]);
    }
    asm volatile("s_waitcnt vmcnt(0)" ::: "memory");
    __syncthreads();
#pragma unroll
    for (int ks = 0; ks < 2; ++ks) {
      int kc = ks * 4 + g;
      short8 av[4], bv[4];
#pragma unroll
      for (int m = 0; m < 4; ++m) {
        int row = wr * 64 + m * 16 + r15;
        av[m] = *(const short8*)&lA[(row * 8 + (kc ^ (row & 7))) * 8];
        int col = wc * 64 + m * 16 + r15;
        bv[m] = *(const short8*)&lB[(col * 8 + (kc ^ (col & 7))) * 8];
      }
#pragma unroll
      for (int m = 0; m < 4; ++m)
#pragma unroll
        for (int n = 0; n < 4; ++n)
          acc[m][n] = __builtin_amdgcn_mfma_f32_16x16x32_bf16(av[m], bv[n], acc[m][n], 0, 0, 0);
    }
    __syncthreads();
  }
#pragma unroll
  for (int n = 0; n < 4; ++n) {
    int col = bcol + wc * 64 + n * 16 + r15;
    float bc = bias[col];
#pragma unroll
    for (int m = 0; m < 4; ++m) {
      int row = brow + wr * 64 + m * 16 + g * 4;
#pragma unroll
      for (int r = 0; r < 4; ++r)
        C[(size_t)(row + r) * DD + col] = acc[m][n][r] + bc;
    }
  }
}

extern "C" void kernel_launch(void* const* d_in, const int* in_sizes, int n_in,
                              void* d_out, int out_size, void* d_ws, size_t ws_size,
                              hipStream_t stream) {
  const float* q  = (const float*)d_in[0];
  const float* k  = (const float*)d_in[1];
  const float* v  = (const float*)d_in[2];
  const float* Wq = (const float*)d_in[3];
  const float* bq = (const float*)d_in[4];
  const float* Wk = (const float*)d_in[5];
  const float* bk = (const float*)d_in[6];
  const float* Wv = (const float*)d_in[7];
  const float* bv = (const float*)d_in[8];
  const float* Wo = (const float*)d_in[9];
  const float* bo = (const float*)d_in[10];
  float* out = (float*)d_out;

  char* ws = (char*)d_ws;
  ushort* vagg  = (ushort*)(ws + 0x0);        // 32 MB bf16 [B*L*D]
  ushort* wvot  = (ushort*)(ws + 0x2100000);  // 512 KB bf16 WvoT
  int*   idx    = (int*)(ws + 0x2388800);     // 256 B
  float* wts    = (float*)(ws + 0x2388900);   // 2 KB
  float* bvo    = (float*)(ws + 0x2389100);   // 2 KB
  int*   counter= (int*)(ws + 0x238A000);     // 4 B
  // colsum partials overlay vagg region (dead until k_conv, stream-ordered):
  float* qpart  = (float*)(ws + 0x0);         // 2 MB [8][128][512]
  float* kpart  = (float*)(ws + 0x200000);    // 2 MB
  // proj partials (dead after projw's last-block stats):
  float* partQ  = (float*)(ws + 0x2180000);   // 128 KB
  float* partK  = (float*)(ws + 0x21A0000);   // 128 KB
  float* partO  = (float*)(ws + 0x21C0000);   // 16 KB

  hipMemsetAsync(counter, 0, sizeof(int), stream);
  k_colsum<<<dim3(16, 8, 2), 512, 0, stream>>>(q, k, qpart, kpart);
  k_projw<<<dim3(152), 256, 0, stream>>>(qpart, kpart, Wq, Wk, bv, Wo, Wv,
                                         bq, bk, bo,
                                         partQ, partK, partO, wvot,
                                         counter, idx, wts, bvo);
  k_conv<<<dim3(64, 4, 8), 256, 0, stream>>>(v, idx, wts, vagg);
  k_gemm<<<dim3(4, 256), 256, 0, stream>>>(vagg, wvot, bvo, out);
}

// Round 13
// 137.169 us; speedup vs baseline: 1.2058x; 1.2058x over previous
//
#include <hip/hip_runtime.h>
#include <hip/hip_bf16.h>

#define LL 4096
#define DD 512
#define BB 8
#define KSEL 41

typedef __attribute__((ext_vector_type(4))) float f32x4;
typedef __attribute__((ext_vector_type(8))) short short8;

__device__ __forceinline__ ushort f2bf(float x) {
  __hip_bfloat16 h = __float2bfloat16(x);
  return *reinterpret_cast<ushort*>(&h);
}

__device__ __forceinline__ void g2lds16(const void* g, void* l) {
  __builtin_amdgcn_global_load_lds(
      (const __attribute__((address_space(1))) unsigned int*)g,
      (__attribute__((address_space(3))) unsigned int*)l, 16, 0, 0);
}

// ---- K1: column sums, wave-sequential streaming + nontemporal loads ----
__global__ __launch_bounds__(512) void k_colsum(const float* __restrict__ q,
                                                const float* __restrict__ kk,
                                                float* __restrict__ qpart,
                                                float* __restrict__ kpart) {
  int lc = blockIdx.x, b = blockIdx.y, which = blockIdx.z;
  const float* src = which ? kk : q;
  float* part = which ? kpart : qpart;
  int lane = threadIdx.x & 63, w = threadIdx.x >> 6;
  int c8 = lane * 8;
  const float* p = src + ((size_t)b * LL + (size_t)lc * 256 + w * 32) * DD + c8;
  float a0 = 0, a1 = 0, a2 = 0, a3 = 0, a4 = 0, a5 = 0, a6 = 0, a7 = 0;
#pragma unroll 8
  for (int l = 0; l < 32; ++l) {
    f32x4 x = __builtin_nontemporal_load((const f32x4*)(p + (size_t)l * DD));
    f32x4 y = __builtin_nontemporal_load((const f32x4*)(p + (size_t)l * DD + 4));
    a0 += x[0]; a1 += x[1]; a2 += x[2]; a3 += x[3];
    a4 += y[0]; a5 += y[1]; a6 += y[2]; a7 += y[3];
  }
  float* dst = &part[((size_t)b * 128 + lc * 8 + w) * DD + c8];
  f32x4 o0 = {a0, a1, a2, a3}, o1 = {a4, a5, a6, a7};
  *(f32x4*)dst = o0;
  *(f32x4*)(dst + 4) = o1;
}

// ---- K2: merged {proj partials (inline colsum reduce)} + {WvoT} (NO fence/stats) ----
__global__ __launch_bounds__(256) void k_projw(
    const float* __restrict__ qpart, const float* __restrict__ kpart,
    const float* __restrict__ Wq, const float* __restrict__ Wk,
    const float* __restrict__ bv, const float* __restrict__ Wo,
    const float* __restrict__ Wv,
    float* __restrict__ partQ, float* __restrict__ partK,
    float* __restrict__ partO, ushort* __restrict__ WT) {
  __shared__ float ss[BB][64];     // proj path (2 KB)
  __shared__ float wv[8][512];     // wvot path (16 KB)
  int bid = blockIdx.x;
  int tid = threadIdx.x;

  if (bid < 24) {
    int jc = bid & 7, which = bid >> 3;
    int j0 = jc * 64;
    if (which == 2) {
      float a0 = 0.f, a1 = 0.f;
      for (int j = 0; j < 64; ++j) {
        float b = bv[j0 + j];
        a0 += b * Wo[(size_t)(j0 + j) * DD + tid];
        a1 += b * Wo[(size_t)(j0 + j) * DD + tid + 256];
      }
      partO[(size_t)jc * DD + tid] = a0;
      partO[(size_t)jc * DD + tid + 256] = a1;
      return;
    }
    const float* part_in = which ? kpart : qpart;
    const float* W = which ? Wk : Wq;
    for (int e = tid; e < BB * 64; e += 256) {
      int b = e >> 6, j = e & 63;
      float s = 0.f;
#pragma unroll 8
      for (int p = 0; p < 128; ++p)
        s += part_in[((size_t)b * 128 + p) * DD + j0 + j];
      ss[b][j] = s;
    }
    __syncthreads();
    float a[BB][2];
#pragma unroll
    for (int b = 0; b < BB; ++b) { a[b][0] = 0.f; a[b][1] = 0.f; }
    for (int j = 0; j < 64; ++j) {
      float w0 = W[(size_t)(j0 + j) * DD + tid];
      float w1 = W[(size_t)(j0 + j) * DD + tid + 256];
#pragma unroll
      for (int b = 0; b < BB; ++b) {
        float sv = ss[b][j];
        a[b][0] += sv * w0;
        a[b][1] += sv * w1;
      }
    }
    float* part = which ? partK : partQ;
#pragma unroll
    for (int b = 0; b < BB; ++b) {
      part[((size_t)jc * BB + b) * DD + tid] = a[b][0];
      part[((size_t)jc * BB + b) * DD + tid + 256] = a[b][1];
    }
    return;
  }

  // ---- wvot path: WT[c][j0..j0+8) = bf16((Wv @ Wo)^T) ----
  int b2 = bid - 24;
  int cb = b2 & 1, jg = b2 >> 1;
  int c = cb * 256 + tid;
  int j0 = jg * 8;
  for (int t = tid; t < 8 * 512; t += 256)
    wv[t >> 9][t & 511] = Wv[(size_t)(j0 + (t >> 9)) * DD + (t & 511)];
  __syncthreads();
  float acc[8] = {0, 0, 0, 0, 0, 0, 0, 0};
  for (int m = 0; m < DD; ++m) {
    float wo = Wo[(size_t)m * DD + c];
#pragma unroll
    for (int j = 0; j < 8; ++j) acc[j] += wv[j][m] * wo;
  }
  ushort4 o0, o1;
  o0.x = f2bf(acc[0]); o0.y = f2bf(acc[1]); o0.z = f2bf(acc[2]); o0.w = f2bf(acc[3]);
  o1.x = f2bf(acc[4]); o1.y = f2bf(acc[5]); o1.z = f2bf(acc[6]); o1.w = f2bf(acc[7]);
  *(ushort4*)&WT[(size_t)c * DD + j0] = o0;
  *(ushort4*)&WT[(size_t)c * DD + j0 + 4] = o1;
}

// ------- K3: reduce proj partials, mean_value, top-41, softmax, bvo -------
__global__ __launch_bounds__(512) void k_stats2(
    const float* __restrict__ partQ, const float* __restrict__ partK,
    const float* __restrict__ partO,
    const float* __restrict__ bq, const float* __restrict__ bk,
    const float* __restrict__ bo,
    int* __restrict__ idx_out, float* __restrict__ wts_out,
    float* __restrict__ bvo_out) {
  __shared__ float Sq[BB][DD];
  __shared__ float Sk[BB][DD];
  __shared__ float mvs[BB][64];
  __shared__ float mab[64];
  __shared__ int idxs[64];
  int tid = threadIdx.x;
  float bqv = bq[tid] * (float)LL, bkv = bk[tid] * (float)LL;
#pragma unroll
  for (int b = 0; b < BB; ++b) {
    float aq = 0.f, ak = 0.f;
#pragma unroll
    for (int jc = 0; jc < 8; ++jc) {
      aq += partQ[((size_t)jc * BB + b) * DD + tid];
      ak += partK[((size_t)jc * BB + b) * DD + tid];
    }
    Sq[b][tid] = aq + bqv;
    Sk[b][tid] = ak + bkv;
  }
  {
    float ao = 0.f;
#pragma unroll
    for (int jc = 0; jc < 8; ++jc) ao += partO[(size_t)jc * DD + tid];
    bvo_out[tid] = ao + bo[tid];
  }
  __syncthreads();
  {
    int b = tid >> 6, d = tid & 63;
    float s = 0.f;
#pragma unroll
    for (int h = 0; h < 8; ++h) s += Sq[b][h * 64 + d] * Sk[b][h * 64 + d];
    mvs[b][d] = s * (1.0f / ((float)LL * 8.0f));
  }
  __syncthreads();
  if (tid < 64) {
    float s = 0.f;
#pragma unroll
    for (int b = 0; b < BB; ++b) s += mvs[b][tid];
    mab[tid] = s * 0.125f;
  }
  __syncthreads();
  if (tid < 64) {
    float x = mab[tid];
    int r = 0;
    for (int d = 0; d < 64; ++d) {
      float y = mab[d];
      r += (y > x || (y == x && d < tid)) ? 1 : 0;
    }
    if (r < KSEL) { idxs[r] = tid; idx_out[r] = tid; }
  }
  __syncthreads();
  if (tid < BB) {
    int b = tid;
    float mx = -3.4e38f;
    for (int i = 0; i < KSEL; ++i) mx = fmaxf(mx, mvs[b][idxs[i]]);
    float s = 0.f;
    for (int i = 0; i < KSEL; ++i) s += expf(mvs[b][idxs[i]] - mx);
    float inv = 1.f / s;
    for (int i = 0; i < KSEL; ++i) wts_out[b * 64 + i] = expf(mvs[b][idxs[i]] - mx) * inv;
  }
}

// -------- K4: vagg = conv(v) via MFMA --------
__global__ __launch_bounds__(256) void k_conv(const float* __restrict__ v,
                                              const int* __restrict__ idx,
                                              const float* __restrict__ wts,
                                              ushort* __restrict__ vagg) {
  __shared__ ushort vwinT[128 * 136];
  __shared__ ushort Mlds[64 * 136];
  __shared__ float coefw[256];
  int lt = blockIdx.x;
  int ch0 = blockIdx.y * 128;
  int b = blockIdx.z;
  int tid = threadIdx.x;
  int l0 = lt * 64;

  coefw[tid] = 0.f;
  __syncthreads();
  if (tid < KSEL) coefw[64 + idx[tid]] = wts[b * 64 + tid];
  __syncthreads();

  {
    int c = tid & 127;
    int jh = tid >> 7;
    const float* vb = v + (size_t)b * LL * DD + ch0 + c;
#pragma unroll
    for (int it = 0; it < 8; ++it) {
      int j0 = (it * 2 + jh) * 8;
      union { unsigned int u[4]; short8 s; } pk;
#pragma unroll
      for (int p = 0; p < 4; ++p) {
        int ja = (l0 + j0 + 2 * p) & (LL - 1);
        int jb = (l0 + j0 + 2 * p + 1) & (LL - 1);
        float lo = vb[(size_t)ja * DD];
        float hi = vb[(size_t)jb * DD];
        pk.u[p] = (unsigned)f2bf(lo) | ((unsigned)f2bf(hi) << 16);
      }
      *(short8*)&vwinT[c * 136 + j0] = pk.s;
    }
  }
#pragma unroll
  for (int it = 0; it < 8; ++it) {
    int e = (it * 256 + tid) * 4;
    int r = e >> 7, j0 = e & 127;
    ushort4 m4;
    m4.x = f2bf(coefw[64 + j0 + 0 - r]);
    m4.y = f2bf(coefw[64 + j0 + 1 - r]);
    m4.z = f2bf(coefw[64 + j0 + 2 - r]);
    m4.w = f2bf(coefw[64 + j0 + 3 - r]);
    *(ushort4*)&Mlds[r * 136 + j0] = m4;
  }
  __syncthreads();

  int lane = tid & 63, w = tid >> 6;
  int r15 = lane & 15, g = lane >> 4;
  f32x4 acc[4][2] = {};
#pragma unroll
  for (int ks = 0; ks < 4; ++ks) {
    int kc = ks * 4 + g;
    short8 av[4], bvv[2];
#pragma unroll
    for (int m = 0; m < 4; ++m)
      av[m] = *(const short8*)&Mlds[(m * 16 + r15) * 136 + kc * 8];
#pragma unroll
    for (int n = 0; n < 2; ++n)
      bvv[n] = *(const short8*)&vwinT[(w * 32 + n * 16 + r15) * 136 + kc * 8];
#pragma unroll
    for (int m = 0; m < 4; ++m)
#pragma unroll
      for (int n = 0; n < 2; ++n)
        acc[m][n] = __builtin_amdgcn_mfma_f32_16x16x32_bf16(av[m], bvv[n], acc[m][n], 0, 0, 0);
  }

  ushort* vout = vagg + ((size_t)b * LL + l0) * DD + ch0;
#pragma unroll
  for (int m = 0; m < 4; ++m)
#pragma unroll
    for (int n = 0; n < 2; ++n)
#pragma unroll
      for (int r = 0; r < 4; ++r) {
        int row = m * 16 + g * 4 + r;
        int col = w * 32 + n * 16 + r15;
        vout[(size_t)row * DD + col] = f2bf(acc[m][n][r]);
      }
}

// -------- K5: out = vagg(bf16) @ Wvo(bf16, stored transposed) + bvo  (f32) --------
// out stores are nontemporal: 64 MB written once, never re-read.
__global__ __launch_bounds__(256) void k_gemm(const ushort* __restrict__ A,
                                              const ushort* __restrict__ BT,
                                              const float* __restrict__ bias,
                                              float* __restrict__ C) {
  __shared__ ushort lA[128 * 64];
  __shared__ ushort lB[128 * 64];
  int bcol = blockIdx.x * 128;
  int brow = blockIdx.y * 128;
  int tid = threadIdx.x;
  int lane = tid & 63, wid = tid >> 6;
  int wr = wid >> 1, wc = wid & 1;
  int r15 = lane & 15, g = lane >> 4;
  f32x4 acc[4][4] = {};
  for (int k0 = 0; k0 < DD; k0 += 64) {
#pragma unroll
    for (int it = 0; it < 4; ++it) {
      int ch = it * 256 + tid;
      int row = ch >> 3;
      int clg = (ch & 7) ^ (row & 7);
      g2lds16(A + (size_t)(brow + row) * DD + k0 + clg * 8, &lA[ch * 8]);
      g2lds16(BT + (size_t)(bcol + row) * DD + k0 + clg * 8, &lB[ch * 8]);
    }
    asm volatile("s_waitcnt vmcnt(0)" ::: "memory");
    __syncthreads();
#pragma unroll
    for (int ks = 0; ks < 2; ++ks) {
      int kc = ks * 4 + g;
      short8 av[4], bv[4];
#pragma unroll
      for (int m = 0; m < 4; ++m) {
        int row = wr * 64 + m * 16 + r15;
        av[m] = *(const short8*)&lA[(row * 8 + (kc ^ (row & 7))) * 8];
        int col = wc * 64 + m * 16 + r15;
        bv[m] = *(const short8*)&lB[(col * 8 + (kc ^ (col & 7))) * 8];
      }
#pragma unroll
      for (int m = 0; m < 4; ++m)
#pragma unroll
        for (int n = 0; n < 4; ++n)
          acc[m][n] = __builtin_amdgcn_mfma_f32_16x16x32_bf16(av[m], bv[n], acc[m][n], 0, 0, 0);
    }
    __syncthreads();
  }
#pragma unroll
  for (int n = 0; n < 4; ++n) {
    int col = bcol + wc * 64 + n * 16 + r15;
    float bc = bias[col];
#pragma unroll
    for (int m = 0; m < 4; ++m) {
      int row = brow + wr * 64 + m * 16 + g * 4;
#pragma unroll
      for (int r = 0; r < 4; ++r)
        __builtin_nontemporal_store(acc[m][n][r] + bc,
                                    &C[(size_t)(row + r) * DD + col]);
    }
  }
}

extern "C" void kernel_launch(void* const* d_in, const int* in_sizes, int n_in,
                              void* d_out, int out_size, void* d_ws, size_t ws_size,
                              hipStream_t stream) {
  const float* q  = (const float*)d_in[0];
  const float* k  = (const float*)d_in[1];
  const float* v  = (const float*)d_in[2];
  const float* Wq = (const float*)d_in[3];
  const float* bq = (const float*)d_in[4];
  const float* Wk = (const float*)d_in[5];
  const float* bk = (const float*)d_in[6];
  const float* Wv = (const float*)d_in[7];
  const float* bv = (const float*)d_in[8];
  const float* Wo = (const float*)d_in[9];
  const float* bo = (const float*)d_in[10];
  float* out = (float*)d_out;

  char* ws = (char*)d_ws;
  ushort* vagg  = (ushort*)(ws + 0x0);        // 32 MB bf16 [B*L*D]
  ushort* wvot  = (ushort*)(ws + 0x2100000);  // 512 KB bf16 WvoT
  int*   idx    = (int*)(ws + 0x2388800);     // 256 B
  float* wts    = (float*)(ws + 0x2388900);   // 2 KB
  float* bvo    = (float*)(ws + 0x2389100);   // 2 KB
  // colsum partials overlay vagg region (dead until k_conv, stream-ordered):
  float* qpart  = (float*)(ws + 0x0);         // 2 MB [8][128][512]
  float* kpart  = (float*)(ws + 0x200000);    // 2 MB
  // proj partials (dead after k_stats2):
  float* partQ  = (float*)(ws + 0x2180000);   // 128 KB
  float* partK  = (float*)(ws + 0x21A0000);   // 128 KB
  float* partO  = (float*)(ws + 0x21C0000);   // 16 KB

  k_colsum<<<dim3(16, 8, 2), 512, 0, stream>>>(q, k, qpart, kpart);
  k_projw<<<dim3(152), 256, 0, stream>>>(qpart, kpart, Wq, Wk, bv, Wo, Wv,
                                         partQ, partK, partO, wvot);
  k_stats2<<<dim3(1), 512, 0, stream>>>(partQ, partK, partO, bq, bk, bo, idx, wts, bvo);
  k_conv<<<dim3(64, 4, 8), 256, 0, stream>>>(v, idx, wts, vagg);
  k_gemm<<<dim3(4, 256), 256, 0, stream>>>(vagg, wvot, bvo, out);
}

// Round 14
// 131.914 us; speedup vs baseline: 1.2538x; 1.0398x over previous
//
#include <hip/hip_runtime.h>
#include <hip/hip_bf16.h>

#define LL 4096
#define DD 512
#define BB 8
#define KSEL 41

typedef __attribute__((ext_vector_type(4))) float f32x4;
typedef __attribute__((ext_vector_type(8))) short short8;

__device__ __forceinline__ ushort f2bf(float x) {
  __hip_bfloat16 h = __float2bfloat16(x);
  return *reinterpret_cast<ushort*>(&h);
}

__device__ __forceinline__ void g2lds16(const void* g, void* l) {
  __builtin_amdgcn_global_load_lds(
      (const __attribute__((address_space(1))) unsigned int*)g,
      (__attribute__((address_space(3))) unsigned int*)l, 16, 0, 0);
}

// ---- K1: column sums, wave-sequential streaming + NT loads, 2 blocks/CU ----
// grid (32 chunks of 128 rows, 8 b, 2 which), 512 thr = 8 waves, 16 rows/wave.
__global__ __launch_bounds__(512) void k_colsum(const float* __restrict__ q,
                                                const float* __restrict__ kk,
                                                float* __restrict__ qpart,
                                                float* __restrict__ kpart) {
  int lc = blockIdx.x, b = blockIdx.y, which = blockIdx.z;
  const float* src = which ? kk : q;
  float* part = which ? kpart : qpart;
  int lane = threadIdx.x & 63, w = threadIdx.x >> 6;
  int c8 = lane * 8;
  const float* p = src + ((size_t)b * LL + (size_t)lc * 128 + w * 16) * DD + c8;
  float a0 = 0, a1 = 0, a2 = 0, a3 = 0, a4 = 0, a5 = 0, a6 = 0, a7 = 0;
#pragma unroll 8
  for (int l = 0; l < 16; ++l) {
    f32x4 x = __builtin_nontemporal_load((const f32x4*)(p + (size_t)l * DD));
    f32x4 y = __builtin_nontemporal_load((const f32x4*)(p + (size_t)l * DD + 4));
    a0 += x[0]; a1 += x[1]; a2 += x[2]; a3 += x[3];
    a4 += y[0]; a5 += y[1]; a6 += y[2]; a7 += y[3];
  }
  // partials: [b][256][512] (32 chunks x 8 waves)
  float* dst = &part[((size_t)b * 256 + lc * 8 + w) * DD + c8];
  f32x4 o0 = {a0, a1, a2, a3}, o1 = {a4, a5, a6, a7};
  *(f32x4*)dst = o0;
  *(f32x4*)(dst + 4) = o1;
}

// ---- K2: merged {proj partials (inline colsum reduce)} + {WvoT} ----
__global__ __launch_bounds__(256) void k_projw(
    const float* __restrict__ qpart, const float* __restrict__ kpart,
    const float* __restrict__ Wq, const float* __restrict__ Wk,
    const float* __restrict__ bv, const float* __restrict__ Wo,
    const float* __restrict__ Wv,
    float* __restrict__ partQ, float* __restrict__ partK,
    float* __restrict__ partO, ushort* __restrict__ WT) {
  __shared__ float ss[BB][64];     // proj path (2 KB)
  __shared__ float wv[8][512];     // wvot path (16 KB)
  int bid = blockIdx.x;
  int tid = threadIdx.x;

  if (bid < 24) {
    int jc = bid & 7, which = bid >> 3;
    int j0 = jc * 64;
    if (which == 2) {
      float a0 = 0.f, a1 = 0.f;
      for (int j = 0; j < 64; ++j) {
        float b = bv[j0 + j];
        a0 += b * Wo[(size_t)(j0 + j) * DD + tid];
        a1 += b * Wo[(size_t)(j0 + j) * DD + tid + 256];
      }
      partO[(size_t)jc * DD + tid] = a0;
      partO[(size_t)jc * DD + tid + 256] = a1;
      return;
    }
    const float* part_in = which ? kpart : qpart;
    const float* W = which ? Wk : Wq;
    for (int e = tid; e < BB * 64; e += 256) {
      int b = e >> 6, j = e & 63;
      float s = 0.f;
#pragma unroll 8
      for (int p = 0; p < 256; ++p)
        s += part_in[((size_t)b * 256 + p) * DD + j0 + j];
      ss[b][j] = s;
    }
    __syncthreads();
    float a[BB][2];
#pragma unroll
    for (int b = 0; b < BB; ++b) { a[b][0] = 0.f; a[b][1] = 0.f; }
    for (int j = 0; j < 64; ++j) {
      float w0 = W[(size_t)(j0 + j) * DD + tid];
      float w1 = W[(size_t)(j0 + j) * DD + tid + 256];
#pragma unroll
      for (int b = 0; b < BB; ++b) {
        float sv = ss[b][j];
        a[b][0] += sv * w0;
        a[b][1] += sv * w1;
      }
    }
    float* part = which ? partK : partQ;
#pragma unroll
    for (int b = 0; b < BB; ++b) {
      part[((size_t)jc * BB + b) * DD + tid] = a[b][0];
      part[((size_t)jc * BB + b) * DD + tid + 256] = a[b][1];
    }
    return;
  }

  // ---- wvot path: WT[c][j0..j0+8) = bf16((Wv @ Wo)^T) ----
  int b2 = bid - 24;
  int cb = b2 & 1, jg = b2 >> 1;
  int c = cb * 256 + tid;
  int j0 = jg * 8;
  for (int t = tid; t < 8 * 512; t += 256)
    wv[t >> 9][t & 511] = Wv[(size_t)(j0 + (t >> 9)) * DD + (t & 511)];
  __syncthreads();
  float acc[8] = {0, 0, 0, 0, 0, 0, 0, 0};
  for (int m = 0; m < DD; ++m) {
    float wo = Wo[(size_t)m * DD + c];
#pragma unroll
    for (int j = 0; j < 8; ++j) acc[j] += wv[j][m] * wo;
  }
  ushort4 o0, o1;
  o0.x = f2bf(acc[0]); o0.y = f2bf(acc[1]); o0.z = f2bf(acc[2]); o0.w = f2bf(acc[3]);
  o1.x = f2bf(acc[4]); o1.y = f2bf(acc[5]); o1.z = f2bf(acc[6]); o1.w = f2bf(acc[7]);
  *(ushort4*)&WT[(size_t)c * DD + j0] = o0;
  *(ushort4*)&WT[(size_t)c * DD + j0 + 4] = o1;
}

// ------- K3: reduce proj partials, mean_value, top-41, softmax, bvo -------
__global__ __launch_bounds__(512) void k_stats2(
    const float* __restrict__ partQ, const float* __restrict__ partK,
    const float* __restrict__ partO,
    const float* __restrict__ bq, const float* __restrict__ bk,
    const float* __restrict__ bo,
    int* __restrict__ idx_out, float* __restrict__ wts_out,
    float* __restrict__ bvo_out) {
  __shared__ float Sq[BB][DD];
  __shared__ float Sk[BB][DD];
  __shared__ float mvs[BB][64];
  __shared__ float mab[64];
  __shared__ int idxs[64];
  int tid = threadIdx.x;
  float bqv = bq[tid] * (float)LL, bkv = bk[tid] * (float)LL;
#pragma unroll
  for (int b = 0; b < BB; ++b) {
    float aq = 0.f, ak = 0.f;
#pragma unroll
    for (int jc = 0; jc < 8; ++jc) {
      aq += partQ[((size_t)jc * BB + b) * DD + tid];
      ak += partK[((size_t)jc * BB + b) * DD + tid];
    }
    Sq[b][tid] = aq + bqv;
    Sk[b][tid] = ak + bkv;
  }
  {
    float ao = 0.f;
#pragma unroll
    for (int jc = 0; jc < 8; ++jc) ao += partO[(size_t)jc * DD + tid];
    bvo_out[tid] = ao + bo[tid];
  }
  __syncthreads();
  {
    int b = tid >> 6, d = tid & 63;
    float s = 0.f;
#pragma unroll
    for (int h = 0; h < 8; ++h) s += Sq[b][h * 64 + d] * Sk[b][h * 64 + d];
    mvs[b][d] = s * (1.0f / ((float)LL * 8.0f));
  }
  __syncthreads();
  if (tid < 64) {
    float s = 0.f;
#pragma unroll
    for (int b = 0; b < BB; ++b) s += mvs[b][tid];
    mab[tid] = s * 0.125f;
  }
  __syncthreads();
  if (tid < 64) {
    float x = mab[tid];
    int r = 0;
    for (int d = 0; d < 64; ++d) {
      float y = mab[d];
      r += (y > x || (y == x && d < tid)) ? 1 : 0;
    }
    if (r < KSEL) { idxs[r] = tid; idx_out[r] = tid; }
  }
  __syncthreads();
  if (tid < BB) {
    int b = tid;
    float mx = -3.4e38f;
    for (int i = 0; i < KSEL; ++i) mx = fmaxf(mx, mvs[b][idxs[i]]);
    float s = 0.f;
    for (int i = 0; i < KSEL; ++i) s += expf(mvs[b][idxs[i]] - mx);
    float inv = 1.f / s;
    for (int i = 0; i < KSEL; ++i) wts_out[b * 64 + i] = expf(mvs[b][idxs[i]] - mx) * inv;
  }
}

// -------- K4: vagg = conv(v) via MFMA --------
__global__ __launch_bounds__(256) void k_conv(const float* __restrict__ v,
                                              const int* __restrict__ idx,
                                              const float* __restrict__ wts,
                                              ushort* __restrict__ vagg) {
  __shared__ ushort vwinT[128 * 136];
  __shared__ ushort Mlds[64 * 136];
  __shared__ float coefw[256];
  int lt = blockIdx.x;
  int ch0 = blockIdx.y * 128;
  int b = blockIdx.z;
  int tid = threadIdx.x;
  int l0 = lt * 64;

  coefw[tid] = 0.f;
  __syncthreads();
  if (tid < KSEL) coefw[64 + idx[tid]] = wts[b * 64 + tid];
  __syncthreads();

  {
    int c = tid & 127;
    int jh = tid >> 7;
    const float* vb = v + (size_t)b * LL * DD + ch0 + c;
#pragma unroll
    for (int it = 0; it < 8; ++it) {
      int j0 = (it * 2 + jh) * 8;
      union { unsigned int u[4]; short8 s; } pk;
#pragma unroll
      for (int p = 0; p < 4; ++p) {
        int ja = (l0 + j0 + 2 * p) & (LL - 1);
        int jb = (l0 + j0 + 2 * p + 1) & (LL - 1);
        float lo = vb[(size_t)ja * DD];
        float hi = vb[(size_t)jb * DD];
        pk.u[p] = (unsigned)f2bf(lo) | ((unsigned)f2bf(hi) << 16);
      }
      *(short8*)&vwinT[c * 136 + j0] = pk.s;
    }
  }
#pragma unroll
  for (int it = 0; it < 8; ++it) {
    int e = (it * 256 + tid) * 4;
    int r = e >> 7, j0 = e & 127;
    ushort4 m4;
    m4.x = f2bf(coefw[64 + j0 + 0 - r]);
    m4.y = f2bf(coefw[64 + j0 + 1 - r]);
    m4.z = f2bf(coefw[64 + j0 + 2 - r]);
    m4.w = f2bf(coefw[64 + j0 + 3 - r]);
    *(ushort4*)&Mlds[r * 136 + j0] = m4;
  }
  __syncthreads();

  int lane = tid & 63, w = tid >> 6;
  int r15 = lane & 15, g = lane >> 4;
  f32x4 acc[4][2] = {};
#pragma unroll
  for (int ks = 0; ks < 4; ++ks) {
    int kc = ks * 4 + g;
    short8 av[4], bvv[2];
#pragma unroll
    for (int m = 0; m < 4; ++m)
      av[m] = *(const short8*)&Mlds[(m * 16 + r15) * 136 + kc * 8];
#pragma unroll
    for (int n = 0; n < 2; ++n)
      bvv[n] = *(const short8*)&vwinT[(w * 32 + n * 16 + r15) * 136 + kc * 8];
#pragma unroll
    for (int m = 0; m < 4; ++m)
#pragma unroll
      for (int n = 0; n < 2; ++n)
        acc[m][n] = __builtin_amdgcn_mfma_f32_16x16x32_bf16(av[m], bvv[n], acc[m][n], 0, 0, 0);
  }

  ushort* vout = vagg + ((size_t)b * LL + l0) * DD + ch0;
#pragma unroll
  for (int m = 0; m < 4; ++m)
#pragma unroll
    for (int n = 0; n < 2; ++n)
#pragma unroll
      for (int r = 0; r < 4; ++r) {
        int row = m * 16 + g * 4 + r;
        int col = w * 32 + n * 16 + r15;
        vout[(size_t)row * DD + col] = f2bf(acc[m][n][r]);
      }
}

// -------- K5: out = vagg(bf16) @ Wvo(bf16, stored transposed) + bvo  (f32) --------
__global__ __launch_bounds__(256) void k_gemm(const ushort* __restrict__ A,
                                              const ushort* __restrict__ BT,
                                              const float* __restrict__ bias,
                                              float* __restrict__ C) {
  __shared__ ushort lA[128 * 64];
  __shared__ ushort lB[128 * 64];
  int bcol = blockIdx.x * 128;
  int brow = blockIdx.y * 128;
  int tid = threadIdx.x;
  int lane = tid & 63, wid = tid >> 6;
  int wr = wid >> 1, wc = wid & 1;
  int r15 = lane & 15, g = lane >> 4;
  f32x4 acc[4][4] = {};
  for (int k0 = 0; k0 < DD; k0 += 64) {
#pragma unroll
    for (int it = 0; it < 4; ++it) {
      int ch = it * 256 + tid;
      int row = ch >> 3;
      int clg = (ch & 7) ^ (row & 7);
      g2lds16(A + (size_t)(brow + row) * DD + k0 + clg * 8, &lA[ch * 8]);
      g2lds16(BT + (size_t)(bcol + row) * DD + k0 + clg * 8, &lB[ch * 8]);
    }
    asm volatile("s_waitcnt vmcnt(0)" ::: "memory");
    __syncthreads();
#pragma unroll
    for (int ks = 0; ks < 2; ++ks) {
      int kc = ks * 4 + g;
      short8 av[4], bv[4];
#pragma unroll
      for (int m = 0; m < 4; ++m) {
        int row = wr * 64 + m * 16 + r15;
        av[m] = *(const short8*)&lA[(row * 8 + (kc ^ (row & 7))) * 8];
        int col = wc * 64 + m * 16 + r15;
        bv[m] = *(const short8*)&lB[(col * 8 + (kc ^ (col & 7))) * 8];
      }
#pragma unroll
      for (int m = 0; m < 4; ++m)
#pragma unroll
        for (int n = 0; n < 4; ++n)
          acc[m][n] = __builtin_amdgcn_mfma_f32_16x16x32_bf16(av[m], bv[n], acc[m][n], 0, 0, 0);
    }
    __syncthreads();
  }
#pragma unroll
  for (int n = 0; n < 4; ++n) {
    int col = bcol + wc * 64 + n * 16 + r15;
    float bc = bias[col];
#pragma unroll
    for (int m = 0; m < 4; ++m) {
      int row = brow + wr * 64 + m * 16 + g * 4;
#pragma unroll
      for (int r = 0; r < 4; ++r)
        C[(size_t)(row + r) * DD + col] = acc[m][n][r] + bc;
    }
  }
}

extern "C" void kernel_launch(void* const* d_in, const int* in_sizes, int n_in,
                              void* d_out, int out_size, void* d_ws, size_t ws_size,
                              hipStream_t stream) {
  const float* q  = (const float*)d_in[0];
  const float* k  = (const float*)d_in[1];
  const float* v  = (const float*)d_in[2];
  const float* Wq = (const float*)d_in[3];
  const float* bq = (const float*)d_in[4];
  const float* Wk = (const float*)d_in[5];
  const float* bk = (const float*)d_in[6];
  const float* Wv = (const float*)d_in[7];
  const float* bv = (const float*)d_in[8];
  const float* Wo = (const float*)d_in[9];
  const float* bo = (const float*)d_in[10];
  float* out = (float*)d_out;

  char* ws = (char*)d_ws;
  ushort* vagg  = (ushort*)(ws + 0x0);        // 32 MB bf16 [B*L*D]
  ushort* wvot  = (ushort*)(ws + 0x2100000);  // 512 KB bf16 WvoT
  int*   idx    = (int*)(ws + 0x2388800);     // 256 B
  float* wts    = (float*)(ws + 0x2388900);   // 2 KB
  float* bvo    = (float*)(ws + 0x2389100);   // 2 KB
  // colsum partials overlay vagg region (dead until k_conv, stream-ordered):
  float* qpart  = (float*)(ws + 0x0);         // 4 MB [8][256][512]
  float* kpart  = (float*)(ws + 0x400000);    // 4 MB
  // proj partials (dead after k_stats2):
  float* partQ  = (float*)(ws + 0x2180000);   // 128 KB
  float* partK  = (float*)(ws + 0x21A0000);   // 128 KB
  float* partO  = (float*)(ws + 0x21C0000);   // 16 KB

  k_colsum<<<dim3(32, 8, 2), 512, 0, stream>>>(q, k, qpart, kpart);
  k_projw<<<dim3(152), 256, 0, stream>>>(qpart, kpart, Wq, Wk, bv, Wo, Wv,
                                         partQ, partK, partO, wvot);
  k_stats2<<<dim3(1), 512, 0, stream>>>(partQ, partK, partO, bq, bk, bo, idx, wts, bvo);
  k_conv<<<dim3(64, 4, 8), 256, 0, stream>>>(v, idx, wts, vagg);
  k_gemm<<<dim3(4, 256), 256, 0, stream>>>(vagg, wvot, bvo, out);
}

// Round 15
// 129.292 us; speedup vs baseline: 1.2792x; 1.0203x over previous
//
#include <hip/hip_runtime.h>
#include <hip/hip_bf16.h>

#define LL 4096
#define DD 512
#define BB 8
#define KSEL 41

typedef __attribute__((ext_vector_type(4))) float f32x4;
typedef __attribute__((ext_vector_type(8))) short short8;

__device__ __forceinline__ ushort f2bf(float x) {
  __hip_bfloat16 h = __float2bfloat16(x);
  return *reinterpret_cast<ushort*>(&h);
}

__device__ __forceinline__ void g2lds16(const void* g, void* l) {
  __builtin_amdgcn_global_load_lds(
      (const __attribute__((address_space(1))) unsigned int*)g,
      (__attribute__((address_space(3))) unsigned int*)l, 16, 0, 0);
}

// ---- K1: column sums, wave-sequential streaming + nontemporal loads ----
// grid (16 chunks of 256 rows, 8 b, 2 which), 512 thr = 8 waves, 32 rows/wave.
__global__ __launch_bounds__(512) void k_colsum(const float* __restrict__ q,
                                                const float* __restrict__ kk,
                                                float* __restrict__ qpart,
                                                float* __restrict__ kpart) {
  int lc = blockIdx.x, b = blockIdx.y, which = blockIdx.z;
  const float* src = which ? kk : q;
  float* part = which ? kpart : qpart;
  int lane = threadIdx.x & 63, w = threadIdx.x >> 6;
  int c8 = lane * 8;
  const float* p = src + ((size_t)b * LL + (size_t)lc * 256 + w * 32) * DD + c8;
  float a0 = 0, a1 = 0, a2 = 0, a3 = 0, a4 = 0, a5 = 0, a6 = 0, a7 = 0;
#pragma unroll 8
  for (int l = 0; l < 32; ++l) {
    f32x4 x = __builtin_nontemporal_load((const f32x4*)(p + (size_t)l * DD));
    f32x4 y = __builtin_nontemporal_load((const f32x4*)(p + (size_t)l * DD + 4));
    a0 += x[0]; a1 += x[1]; a2 += x[2]; a3 += x[3];
    a4 += y[0]; a5 += y[1]; a6 += y[2]; a7 += y[3];
  }
  float* dst = &part[((size_t)b * 128 + lc * 8 + w) * DD + c8];
  f32x4 o0 = {a0, a1, a2, a3}, o1 = {a4, a5, a6, a7};
  *(f32x4*)dst = o0;
  *(f32x4*)(dst + 4) = o1;
}

// ---- K2: merged {proj partials (inline colsum reduce)} + {WvoT} ----
__global__ __launch_bounds__(256) void k_projw(
    const float* __restrict__ qpart, const float* __restrict__ kpart,
    const float* __restrict__ Wq, const float* __restrict__ Wk,
    const float* __restrict__ bv, const float* __restrict__ Wo,
    const float* __restrict__ Wv,
    float* __restrict__ partQ, float* __restrict__ partK,
    float* __restrict__ partO, ushort* __restrict__ WT) {
  __shared__ float ss[BB][64];     // proj path (2 KB)
  __shared__ float wv[8][512];     // wvot path (16 KB)
  int bid = blockIdx.x;
  int tid = threadIdx.x;

  if (bid < 24) {
    int jc = bid & 7, which = bid >> 3;
    int j0 = jc * 64;
    if (which == 2) {
      float a0 = 0.f, a1 = 0.f;
      for (int j = 0; j < 64; ++j) {
        float b = bv[j0 + j];
        a0 += b * Wo[(size_t)(j0 + j) * DD + tid];
        a1 += b * Wo[(size_t)(j0 + j) * DD + tid + 256];
      }
      partO[(size_t)jc * DD + tid] = a0;
      partO[(size_t)jc * DD + tid + 256] = a1;
      return;
    }
    const float* part_in = which ? kpart : qpart;
    const float* W = which ? Wk : Wq;
    for (int e = tid; e < BB * 64; e += 256) {
      int b = e >> 6, j = e & 63;
      float s = 0.f;
#pragma unroll 8
      for (int p = 0; p < 128; ++p)
        s += part_in[((size_t)b * 128 + p) * DD + j0 + j];
      ss[b][j] = s;
    }
    __syncthreads();
    float a[BB][2];
#pragma unroll
    for (int b = 0; b < BB; ++b) { a[b][0] = 0.f; a[b][1] = 0.f; }
    for (int j = 0; j < 64; ++j) {
      float w0 = W[(size_t)(j0 + j) * DD + tid];
      float w1 = W[(size_t)(j0 + j) * DD + tid + 256];
#pragma unroll
      for (int b = 0; b < BB; ++b) {
        float sv = ss[b][j];
        a[b][0] += sv * w0;
        a[b][1] += sv * w1;
      }
    }
    float* part = which ? partK : partQ;
#pragma unroll
    for (int b = 0; b < BB; ++b) {
      part[((size_t)jc * BB + b) * DD + tid] = a[b][0];
      part[((size_t)jc * BB + b) * DD + tid + 256] = a[b][1];
    }
    return;
  }

  // ---- wvot path: WT[c][j0..j0+8) = bf16((Wv @ Wo)^T) ----
  int b2 = bid - 24;
  int cb = b2 & 1, jg = b2 >> 1;
  int c = cb * 256 + tid;
  int j0 = jg * 8;
  for (int t = tid; t < 8 * 512; t += 256)
    wv[t >> 9][t & 511] = Wv[(size_t)(j0 + (t >> 9)) * DD + (t & 511)];
  __syncthreads();
  float acc[8] = {0, 0, 0, 0, 0, 0, 0, 0};
  for (int m = 0; m < DD; ++m) {
    float wo = Wo[(size_t)m * DD + c];
#pragma unroll
    for (int j = 0; j < 8; ++j) acc[j] += wv[j][m] * wo;
  }
  ushort4 o0, o1;
  o0.x = f2bf(acc[0]); o0.y = f2bf(acc[1]); o0.z = f2bf(acc[2]); o0.w = f2bf(acc[3]);
  o1.x = f2bf(acc[4]); o1.y = f2bf(acc[5]); o1.z = f2bf(acc[6]); o1.w = f2bf(acc[7]);
  *(ushort4*)&WT[(size_t)c * DD + j0] = o0;
  *(ushort4*)&WT[(size_t)c * DD + j0 + 4] = o1;
}

// ------- K3: reduce proj partials, mean_value, top-41, softmax, bvo -------
__global__ __launch_bounds__(512) void k_stats2(
    const float* __restrict__ partQ, const float* __restrict__ partK,
    const float* __restrict__ partO,
    const float* __restrict__ bq, const float* __restrict__ bk,
    const float* __restrict__ bo,
    int* __restrict__ idx_out, float* __restrict__ wts_out,
    float* __restrict__ bvo_out) {
  __shared__ float Sq[BB][DD];
  __shared__ float Sk[BB][DD];
  __shared__ float mvs[BB][64];
  __shared__ float mab[64];
  __shared__ int idxs[64];
  int tid = threadIdx.x;
  float bqv = bq[tid] * (float)LL, bkv = bk[tid] * (float)LL;
#pragma unroll
  for (int b = 0; b < BB; ++b) {
    float aq = 0.f, ak = 0.f;
#pragma unroll
    for (int jc = 0; jc < 8; ++jc) {
      aq += partQ[((size_t)jc * BB + b) * DD + tid];
      ak += partK[((size_t)jc * BB + b) * DD + tid];
    }
    Sq[b][tid] = aq + bqv;
    Sk[b][tid] = ak + bkv;
  }
  {
    float ao = 0.f;
#pragma unroll
    for (int jc = 0; jc < 8; ++jc) ao += partO[(size_t)jc * DD + tid];
    bvo_out[tid] = ao + bo[tid];
  }
  __syncthreads();
  {
    int b = tid >> 6, d = tid & 63;
    float s = 0.f;
#pragma unroll
    for (int h = 0; h < 8; ++h) s += Sq[b][h * 64 + d] * Sk[b][h * 64 + d];
    mvs[b][d] = s * (1.0f / ((float)LL * 8.0f));
  }
  __syncthreads();
  if (tid < 64) {
    float s = 0.f;
#pragma unroll
    for (int b = 0; b < BB; ++b) s += mvs[b][tid];
    mab[tid] = s * 0.125f;
  }
  __syncthreads();
  if (tid < 64) {
    float x = mab[tid];
    int r = 0;
    for (int d = 0; d < 64; ++d) {
      float y = mab[d];
      r += (y > x || (y == x && d < tid)) ? 1 : 0;
    }
    if (r < KSEL) { idxs[r] = tid; idx_out[r] = tid; }
  }
  __syncthreads();
  if (tid < BB) {
    int b = tid;
    float mx = -3.4e38f;
    for (int i = 0; i < KSEL; ++i) mx = fmaxf(mx, mvs[b][idxs[i]]);
    float s = 0.f;
    for (int i = 0; i < KSEL; ++i) s += expf(mvs[b][idxs[i]] - mx);
    float inv = 1.f / s;
    for (int i = 0; i < KSEL; ++i) wts_out[b * 64 + i] = expf(mvs[b][idxs[i]] - mx) * inv;
  }
}

// -------- K4: vagg = conv(v) via MFMA --------
__global__ __launch_bounds__(256) void k_conv(const float* __restrict__ v,
                                              const int* __restrict__ idx,
                                              const float* __restrict__ wts,
                                              ushort* __restrict__ vagg) {
  __shared__ ushort vwinT[128 * 136];
  __shared__ ushort Mlds[64 * 136];
  __shared__ float coefw[256];
  int lt = blockIdx.x;
  int ch0 = blockIdx.y * 128;
  int b = blockIdx.z;
  int tid = threadIdx.x;
  int l0 = lt * 64;

  coefw[tid] = 0.f;
  __syncthreads();
  if (tid < KSEL) coefw[64 + idx[tid]] = wts[b * 64 + tid];
  __syncthreads();

  {
    int c = tid & 127;
    int jh = tid >> 7;
    const float* vb = v + (size_t)b * LL * DD + ch0 + c;
#pragma unroll
    for (int it = 0; it < 8; ++it) {
      int j0 = (it * 2 + jh) * 8;
      union { unsigned int u[4]; short8 s; } pk;
#pragma unroll
      for (int p = 0; p < 4; ++p) {
        int ja = (l0 + j0 + 2 * p) & (LL - 1);
        int jb = (l0 + j0 + 2 * p + 1) & (LL - 1);
        float lo = vb[(size_t)ja * DD];
        float hi = vb[(size_t)jb * DD];
        pk.u[p] = (unsigned)f2bf(lo) | ((unsigned)f2bf(hi) << 16);
      }
      *(short8*)&vwinT[c * 136 + j0] = pk.s;
    }
  }
#pragma unroll
  for (int it = 0; it < 8; ++it) {
    int e = (it * 256 + tid) * 4;
    int r = e >> 7, j0 = e & 127;
    ushort4 m4;
    m4.x = f2bf(coefw[64 + j0 + 0 - r]);
    m4.y = f2bf(coefw[64 + j0 + 1 - r]);
    m4.z = f2bf(coefw[64 + j0 + 2 - r]);
    m4.w = f2bf(coefw[64 + j0 + 3 - r]);
    *(ushort4*)&Mlds[r * 136 + j0] = m4;
  }
  __syncthreads();

  int lane = tid & 63, w = tid >> 6;
  int r15 = lane & 15, g = lane >> 4;
  f32x4 acc[4][2] = {};
#pragma unroll
  for (int ks = 0; ks < 4; ++ks) {
    int kc = ks * 4 + g;
    short8 av[4], bvv[2];
#pragma unroll
    for (int m = 0; m < 4; ++m)
      av[m] = *(const short8*)&Mlds[(m * 16 + r15) * 136 + kc * 8];
#pragma unroll
    for (int n = 0; n < 2; ++n)
      bvv[n] = *(const short8*)&vwinT[(w * 32 + n * 16 + r15) * 136 + kc * 8];
#pragma unroll
    for (int m = 0; m < 4; ++m)
#pragma unroll
      for (int n = 0; n < 2; ++n)
        acc[m][n] = __builtin_amdgcn_mfma_f32_16x16x32_bf16(av[m], bvv[n], acc[m][n], 0, 0, 0);
  }

  ushort* vout = vagg + ((size_t)b * LL + l0) * DD + ch0;
#pragma unroll
  for (int m = 0; m < 4; ++m)
#pragma unroll
    for (int n = 0; n < 2; ++n)
#pragma unroll
      for (int r = 0; r < 4; ++r) {
        int row = m * 16 + g * 4 + r;
        int col = w * 32 + n * 16 + r15;
        vout[(size_t)row * DD + col] = f2bf(acc[m][n][r]);
      }
}

// -------- K5: out = vagg(bf16) @ Wvo(bf16, stored transposed) + bvo  (f32) --------
__global__ __launch_bounds__(256) void k_gemm(const ushort* __restrict__ A,
                                              const ushort* __restrict__ BT,
                                              const float* __restrict__ bias,
                                              float* __restrict__ C) {
  __shared__ ushort lA[128 * 64];
  __shared__ ushort lB[128 * 64];
  int bcol = blockIdx.x * 128;
  int brow = blockIdx.y * 128;
  int tid = threadIdx.x;
  int lane = tid & 63, wid = tid >> 6;
  int wr = wid >> 1, wc = wid & 1;
  int r15 = lane & 15, g = lane >> 4;
  f32x4 acc[4][4] = {};
  for (int k0 = 0; k0 < DD; k0 += 64) {
#pragma unroll
    for (int it = 0; it < 4; ++it) {
      int ch = it * 256 + tid;
      int row = ch >> 3;
      int clg = (ch & 7) ^ (row & 7);
      g2lds16(A + (size_t)(brow + row) * DD + k0 + clg * 8, &lA[ch * 8]);
      g2lds16(BT + (size_t)(bcol + row) * DD + k0 + clg * 8, &lB[ch * 8]);
    }
    asm volatile("s_waitcnt vmcnt(0)" ::: "memory");
    __syncthreads();
#pragma unroll
    for (int ks = 0; ks < 2; ++ks) {
      int kc = ks * 4 + g;
      short8 av[4], bv[4];
#pragma unroll
      for (int m = 0; m < 4; ++m) {
        int row = wr * 64 + m * 16 + r15;
        av[m] = *(const short8*)&lA[(row * 8 + (kc ^ (row & 7))) * 8];
        int col = wc * 64 + m * 16 + r15;
        bv[m] = *(const short8*)&lB[(col * 8 + (kc ^ (col & 7))) * 8];
      }
#pragma unroll
      for (int m = 0; m < 4; ++m)
#pragma unroll
        for (int n = 0; n < 4; ++n)
          acc[m][n] = __builtin_amdgcn_mfma_f32_16x16x32_bf16(av[m], bv[n], acc[m][n], 0, 0, 0);
    }
    __syncthreads();
  }
#pragma unroll
  for (int n = 0; n < 4; ++n) {
    int col = bcol + wc * 64 + n * 16 + r15;
    float bc = bias[col];
#pragma unroll
    for (int m = 0; m < 4; ++m) {
      int row = brow + wr * 64 + m * 16 + g * 4;
#pragma unroll
      for (int r = 0; r < 4; ++r)
        C[(size_t)(row + r) * DD + col] = acc[m][n][r] + bc;
    }
  }
}

extern "C" void kernel_launch(void* const* d_in, const int* in_sizes, int n_in,
                              void* d_out, int out_size, void* d_ws, size_t ws_size,
                              hipStream_t stream) {
  const float* q  = (const float*)d_in[0];
  const float* k  = (const float*)d_in[1];
  const float* v  = (const float*)d_in[2];
  const float* Wq = (const float*)d_in[3];
  const float* bq = (const float*)d_in[4];
  const float* Wk = (const float*)d_in[5];
  const float* bk = (const float*)d_in[6];
  const float* Wv = (const float*)d_in[7];
  const float* bv = (const float*)d_in[8];
  const float* Wo = (const float*)d_in[9];
  const float* bo = (const float*)d_in[10];
  float* out = (float*)d_out;

  char* ws = (char*)d_ws;
  ushort* vagg  = (ushort*)(ws + 0x0);        // 32 MB bf16 [B*L*D]
  ushort* wvot  = (ushort*)(ws + 0x2100000);  // 512 KB bf16 WvoT
  int*   idx    = (int*)(ws + 0x2388800);     // 256 B
  float* wts    = (float*)(ws + 0x2388900);   // 2 KB
  float* bvo    = (float*)(ws + 0x2389100);   // 2 KB
  // colsum partials overlay vagg region (dead until k_conv, stream-ordered):
  float* qpart  = (float*)(ws + 0x0);         // 2 MB [8][128][512]
  float* kpart  = (float*)(ws + 0x200000);    // 2 MB
  // proj partials (dead after k_stats2):
  float* partQ  = (float*)(ws + 0x2180000);   // 128 KB
  float* partK  = (float*)(ws + 0x21A0000);   // 128 KB
  float* partO  = (float*)(ws + 0x21C0000);   // 16 KB

  k_colsum<<<dim3(16, 8, 2), 512, 0, stream>>>(q, k, qpart, kpart);
  k_projw<<<dim3(152), 256, 0, stream>>>(qpart, kpart, Wq, Wk, bv, Wo, Wv,
                                         partQ, partK, partO, wvot);
  k_stats2<<<dim3(1), 512, 0, stream>>>(partQ, partK, partO, bq, bk, bo, idx, wts, bvo);
  k_conv<<<dim3(64, 4, 8), 256, 0, stream>>>(v, idx, wts, vagg);
  k_gemm<<<dim3(4, 256), 256, 0, stream>>>(vagg, wvot, bvo, out);
}